// Round 1
// baseline (1697.060 us; speedup 1.0000x reference)
//
#include <hip/hip_runtime.h>
#include <stdint.h>

// GlobalEmdModel: mlp1(128->256->512->512) -> segmax -> segbias trick ->
// mlp2(X@W4a + sb[seg] -> 512 -> segmax) ; bf16 MFMA GEMMs, fp32 epilogues.

typedef __bf16 bf16;
typedef __bf16 bf16x4 __attribute__((ext_vector_type(4)));
typedef __bf16 bf16x8 __attribute__((ext_vector_type(8)));
typedef float f32x4 __attribute__((ext_vector_type(4)));

#define N_PTS 400000
#define ORD_NEG_INF 0x007FFFFFu  // f2ord(-inf)

__device__ __forceinline__ unsigned f2ord(float f) {
  unsigned u = __float_as_uint(f);
  return (u & 0x80000000u) ? ~u : (u | 0x80000000u);
}
__device__ __forceinline__ float ord2f(unsigned o) {
  unsigned u = (o & 0x80000000u) ? (o ^ 0x80000000u) : ~o;
  return __uint_as_float(u);
}

__device__ __forceinline__ void gld16(const bf16* g, bf16* l) {
  __builtin_amdgcn_global_load_lds((const __attribute__((address_space(1))) void*)g,
                                   (__attribute__((address_space(3))) void*)l, 16, 0, 0);
}

__global__ void k_init(unsigned* g_ord, unsigned* out_u) {
  int i = blockIdx.x * 256 + threadIdx.x;
  if (i < 64 * 512) { g_ord[i] = ORD_NEG_INF; out_u[i] = ORD_NEG_INF; }
}

__global__ void k_convX(const float* __restrict__ x, bf16* __restrict__ y, long n4) {
  long i = (long)blockIdx.x * 256 + threadIdx.x;
  long stride = (long)gridDim.x * 256;
  for (; i < n4; i += stride) {
    float4 v = ((const float4*)x)[i];
    bf16x4 o = {(bf16)v.x, (bf16)v.y, (bf16)v.z, (bf16)v.w};
    ((bf16x4*)y)[i] = o;
  }
}

// W [K][Nout] fp32 -> Wt [Nout][K] bf16
__global__ void k_convWt(const float* __restrict__ W, bf16* __restrict__ Wt, int K, int Nout) {
  int idx = blockIdx.x * 256 + threadIdx.x;
  if (idx < K * Nout) {
    int k = idx / Nout, c = idx - k * Nout;
    Wt[(size_t)c * K + k] = (bf16)W[idx];
  }
}

// sb[s][c] = b4[c] + sum_j g[s][j] * W4[128+j][c]
__global__ void k_segbias(const unsigned* __restrict__ g_ord, const float* __restrict__ W4,
                          const float* __restrict__ b4, float* __restrict__ sb) {
  const int s = blockIdx.x, c = threadIdx.x;
  __shared__ float gs[512];
  gs[c] = ord2f(g_ord[s * 512 + c]);
  __syncthreads();
  float acc = b4[c];
  for (int j = 0; j < 512; ++j) acc = fmaf(gs[j], W4[(size_t)(128 + j) * 512 + c], acc);
  sb[s * 512 + c] = acc;
}

__global__ void k_decode(unsigned* p, int n) {
  int i = blockIdx.x * 256 + threadIdx.x;
  if (i < n) { float f = ord2f(p[i]); ((float*)p)[i] = f; }
}

// BIASMODE: 0 = per-col bias[], 1 = per-(seg,col) sb[]  (Nout must be 512)
// EPI: 0 = store bf16 to out, 1 = segmax atomicMax(ordered-uint) into outAtomic
template <int BIASMODE, bool RELU, int EPI>
__launch_bounds__(256)
__global__ void k_gemm(const bf16* __restrict__ A, const bf16* __restrict__ Bt, int K,
                       const float* __restrict__ bias, const int* __restrict__ ids,
                       long row_off, bf16* __restrict__ out,
                       unsigned* __restrict__ outAtomic, int Nout) {
  __shared__ __align__(16) bf16 sA[128 * 32];
  __shared__ __align__(16) bf16 sB[128 * 32];
  __shared__ int sIds[128];
  const int tid = threadIdx.x;
  const int wid = tid >> 6, lane = tid & 63;
  const int m0 = blockIdx.x * 128, n0 = blockIdx.y * 128;

  if ((BIASMODE == 1 || EPI == 1) && tid < 128) sIds[tid] = ids[row_off + m0 + tid];

  // staging geometry: 512 chunks of 16B per tile; chunk c -> row c>>2, colchunk c&3
  const int c0 = wid * 64 + lane;  // first issue; second adds 256 (== +64 rows)
  const bf16* gA0 = A + (size_t)(m0 + (c0 >> 2)) * K + (c0 & 3) * 8;
  const bf16* gA1 = gA0 + (size_t)64 * K;
  const bf16* gB0 = Bt + (size_t)(n0 + (c0 >> 2)) * K + (c0 & 3) * 8;
  const bf16* gB1 = gB0 + (size_t)64 * K;
  bf16* lA0 = &sA[wid * 512]; bf16* lA1 = &sA[(wid + 4) * 512];
  bf16* lB0 = &sB[wid * 512]; bf16* lB1 = &sB[(wid + 4) * 512];

  const int wr = wid >> 1, wc = wid & 1;
  const int lr = lane & 15, lk = lane >> 4;
  const bf16* pA = &sA[(wr * 64 + lr) * 32 + lk * 8];
  const bf16* pB = &sB[(wc * 64 + lr) * 32 + lk * 8];

  f32x4 acc[4][4];
#pragma unroll
  for (int i = 0; i < 4; ++i)
#pragma unroll
    for (int j = 0; j < 4; ++j) acc[i][j] = {0.f, 0.f, 0.f, 0.f};

  const int KT = K >> 5;
  // prologue
  gld16(gA0, lA0); gld16(gA1, lA1); gld16(gB0, lB0); gld16(gB1, lB1);
  for (int kt = 0; kt < KT; ++kt) {
    asm volatile("s_waitcnt vmcnt(0)" ::: "memory");
    __syncthreads();
    bf16x8 af[4], bfr[4];
#pragma unroll
    for (int i = 0; i < 4; ++i) af[i] = *(const bf16x8*)(pA + i * 16 * 32);
#pragma unroll
    for (int i = 0; i < 4; ++i) bfr[i] = *(const bf16x8*)(pB + i * 16 * 32);
#pragma unroll
    for (int i = 0; i < 4; ++i)
#pragma unroll
      for (int j = 0; j < 4; ++j)
        acc[i][j] = __builtin_amdgcn_mfma_f32_16x16x32_bf16(af[i], bfr[j], acc[i][j], 0, 0, 0);
    __syncthreads();
    if (kt + 1 < KT) {
      const int ko = (kt + 1) * 32;
      gld16(gA0 + ko, lA0); gld16(gA1 + ko, lA1);
      gld16(gB0 + ko, lB0); gld16(gB1 + ko, lB1);
    }
  }

  if constexpr (EPI == 0) {
#pragma unroll
    for (int j = 0; j < 4; ++j) {
      const int col = n0 + wc * 64 + j * 16 + lr;
      float bcol = (BIASMODE == 0) ? bias[col] : 0.f;
#pragma unroll
      for (int i = 0; i < 4; ++i) {
#pragma unroll
        for (int q = 0; q < 4; ++q) {
          const int rl = wr * 64 + i * 16 + lk * 4 + q;
          float v = acc[i][j][q];
          if constexpr (BIASMODE == 0) v += bcol;
          else v += bias[(size_t)sIds[rl] * 512 + col];
          if constexpr (RELU) v = fmaxf(v, 0.f);
          out[(size_t)(m0 + rl) * Nout + col] = (bf16)v;
        }
      }
    }
  } else {
    const int sLo = sIds[wr * 64], sHi = sIds[wr * 64 + 63];
#pragma unroll
    for (int j = 0; j < 4; ++j) {
      const int col = n0 + wc * 64 + j * 16 + lr;
      const float bcol = bias[col];
      for (int s = sLo; s <= sHi; ++s) {
        float m = -__builtin_inff();
#pragma unroll
        for (int i = 0; i < 4; ++i)
#pragma unroll
          for (int q = 0; q < 4; ++q) {
            const int rl = wr * 64 + i * 16 + lk * 4 + q;
            float v = acc[i][j][q] + bcol;
            m = (sIds[rl] == s) ? fmaxf(m, v) : m;
          }
        m = fmaxf(m, __shfl_xor(m, 16));
        m = fmaxf(m, __shfl_xor(m, 32));
        if (lane < 16) atomicMax(&outAtomic[(size_t)s * 512 + col], f2ord(m));
      }
    }
  }
}

static inline long lmin(long a, long b) { return a < b ? a : b; }

extern "C" void kernel_launch(void* const* d_in, const int* in_sizes, int n_in,
                              void* d_out, int out_size, void* d_ws, size_t ws_size,
                              hipStream_t stream) {
  const float* pos = (const float*)d_in[0];
  const int* ids = (const int*)d_in[1];
  const float* W1 = (const float*)d_in[2]; const float* b1 = (const float*)d_in[3];
  const float* W2 = (const float*)d_in[4]; const float* b2 = (const float*)d_in[5];
  const float* W3 = (const float*)d_in[6]; const float* b3 = (const float*)d_in[7];
  const float* W4 = (const float*)d_in[8]; const float* b4 = (const float*)d_in[9];
  const float* W5 = (const float*)d_in[10]; const float* b5 = (const float*)d_in[11];

  char* ws = (char*)d_ws;
  size_t off = 0;
  auto alloc = [&](size_t bytes) -> char* {
    off = (off + 255) & ~(size_t)255;
    char* p = ws + off; off += bytes; return p;
  };
  bf16* Wt1  = (bf16*)alloc(128 * 256 * 2);
  bf16* Wt2  = (bf16*)alloc(256 * 512 * 2);
  bf16* Wt3  = (bf16*)alloc(512 * 512 * 2);
  bf16* Wt4a = (bf16*)alloc(128 * 512 * 2);
  bf16* Wt5  = (bf16*)alloc(512 * 512 * 2);
  unsigned* g_ord = (unsigned*)alloc(64 * 512 * 4);
  float* sb = (float*)alloc(64 * 512 * 4);

  const size_t per_row = (128 + 256 + 512) * 2;
  size_t fixed_end = (off + 255) & ~(size_t)255;
  long avail = (long)ws_size - (long)fixed_end - 8192;
  long chunk = (avail / (long)per_row) & ~127L;
  if (chunk > N_PTS) chunk = N_PTS;
  if (chunk < 128) chunk = 128;  // ws too small -> will fault; nothing to do

  bf16* Xbf = (bf16*)alloc((size_t)chunk * 128 * 2);
  bf16* h1  = (bf16*)alloc((size_t)chunk * 256 * 2);
  bf16* h2  = (bf16*)alloc((size_t)chunk * 512 * 2);  // also z1 in phase 2

  const int nChunks = (int)((N_PTS + chunk - 1) / chunk);

  k_init<<<dim3(128), dim3(256), 0, stream>>>(g_ord, (unsigned*)d_out);
  k_convWt<<<dim3((128 * 256 + 255) / 256), dim3(256), 0, stream>>>(W1, Wt1, 128, 256);
  k_convWt<<<dim3((256 * 512 + 255) / 256), dim3(256), 0, stream>>>(W2, Wt2, 256, 512);
  k_convWt<<<dim3((512 * 512 + 255) / 256), dim3(256), 0, stream>>>(W3, Wt3, 512, 512);
  k_convWt<<<dim3((128 * 512 + 255) / 256), dim3(256), 0, stream>>>(W4, Wt4a, 128, 512);
  k_convWt<<<dim3((512 * 512 + 255) / 256), dim3(256), 0, stream>>>(W5, Wt5, 512, 512);

  // phase 1: mlp1 + fused segmax -> g_ord
  for (long o = 0; o < N_PTS; o += chunk) {
    long rows = lmin(chunk, N_PTS - o);
    long n4 = rows * 32;
    long cb = lmin(2048, (n4 + 255) / 256);
    k_convX<<<dim3((unsigned)cb), dim3(256), 0, stream>>>(pos + o * 128, Xbf, n4);
    dim3 g1((unsigned)(rows / 128), 2), g2((unsigned)(rows / 128), 4);
    k_gemm<0, true, 0><<<g1, dim3(256), 0, stream>>>(Xbf, Wt1, 128, b1, ids, o, h1, nullptr, 256);
    k_gemm<0, true, 0><<<g2, dim3(256), 0, stream>>>(h1, Wt2, 256, b2, ids, o, h2, nullptr, 512);
    k_gemm<0, false, 1><<<g2, dim3(256), 0, stream>>>(h2, Wt3, 512, b3, ids, o, nullptr, g_ord, 512);
  }
  k_segbias<<<dim3(64), dim3(512), 0, stream>>>(g_ord, W4, b4, sb);
  // phase 2: z1 = relu(X@W4a + sb[seg]); out = segmax(z1@W5 + b5)
  for (long o = 0; o < N_PTS; o += chunk) {
    long rows = lmin(chunk, N_PTS - o);
    if (nChunks > 1) {
      long n4 = rows * 32;
      long cb = lmin(2048, (n4 + 255) / 256);
      k_convX<<<dim3((unsigned)cb), dim3(256), 0, stream>>>(pos + o * 128, Xbf, n4);
    }
    dim3 g2((unsigned)(rows / 128), 4);
    k_gemm<1, true, 0><<<g2, dim3(256), 0, stream>>>(Xbf, Wt4a, 128, sb, ids, o, h2, nullptr, 512);
    k_gemm<0, false, 1><<<g2, dim3(256), 0, stream>>>(h2, Wt5, 512, b5, ids, o, nullptr, (unsigned*)d_out, 512);
  }
  k_decode<<<dim3(128), dim3(256), 0, stream>>>((unsigned*)d_out, 64 * 512);
}

// Round 2
// 1307.716 us; speedup vs baseline: 1.2977x; 1.2977x over previous
//
#include <hip/hip_runtime.h>
#include <stdint.h>

// GlobalEmdModel: mlp1(128->256->512->512) -> segmax -> segbias trick ->
// mlp2(X@W4a + sb[seg] -> 512 -> segmax) ; bf16 MFMA GEMMs, fp32 epilogues.
// R2: dbuf + counted vmcnt(4), LDS XOR swizzle (2-way), N-fast grid + XCD swizzle.

typedef __bf16 bf16;
typedef __bf16 bf16x4 __attribute__((ext_vector_type(4)));
typedef __bf16 bf16x8 __attribute__((ext_vector_type(8)));
typedef float f32x4 __attribute__((ext_vector_type(4)));

#define N_PTS 400000
#define ORD_NEG_INF 0x007FFFFFu  // f2ord(-inf)

__device__ __forceinline__ unsigned f2ord(float f) {
  unsigned u = __float_as_uint(f);
  return (u & 0x80000000u) ? ~u : (u | 0x80000000u);
}
__device__ __forceinline__ float ord2f(unsigned o) {
  unsigned u = (o & 0x80000000u) ? (o ^ 0x80000000u) : ~o;
  return __uint_as_float(u);
}

__device__ __forceinline__ void gld16(const bf16* g, bf16* l) {
  __builtin_amdgcn_global_load_lds((const __attribute__((address_space(1))) void*)g,
                                   (__attribute__((address_space(3))) void*)l, 16, 0, 0);
}

__global__ void k_init(unsigned* g_ord, unsigned* out_u) {
  int i = blockIdx.x * 256 + threadIdx.x;
  if (i < 64 * 512) { g_ord[i] = ORD_NEG_INF; out_u[i] = ORD_NEG_INF; }
}

__global__ void k_convX(const float* __restrict__ x, bf16* __restrict__ y, long n4) {
  long i = (long)blockIdx.x * 256 + threadIdx.x;
  long stride = (long)gridDim.x * 256;
  for (; i < n4; i += stride) {
    float4 v = ((const float4*)x)[i];
    bf16x4 o = {(bf16)v.x, (bf16)v.y, (bf16)v.z, (bf16)v.w};
    ((bf16x4*)y)[i] = o;
  }
}

// W [K][Nout] fp32 -> Wt [Nout][K] bf16
__global__ void k_convWt(const float* __restrict__ W, bf16* __restrict__ Wt, int K, int Nout) {
  int idx = blockIdx.x * 256 + threadIdx.x;
  if (idx < K * Nout) {
    int k = idx / Nout, c = idx - k * Nout;
    Wt[(size_t)c * K + k] = (bf16)W[idx];
  }
}

// sb[s][c] = b4[c] + sum_j g[s][j] * W4[128+j][c]
__global__ void k_segbias(const unsigned* __restrict__ g_ord, const float* __restrict__ W4,
                          const float* __restrict__ b4, float* __restrict__ sb) {
  const int s = blockIdx.x, c = threadIdx.x;
  __shared__ float gs[512];
  gs[c] = ord2f(g_ord[s * 512 + c]);
  __syncthreads();
  float acc = b4[c];
  for (int j = 0; j < 512; ++j) acc = fmaf(gs[j], W4[(size_t)(128 + j) * 512 + c], acc);
  sb[s * 512 + c] = acc;
}

__global__ void k_decode(unsigned* p, int n) {
  int i = blockIdx.x * 256 + threadIdx.x;
  if (i < n) { float f = ord2f(p[i]); ((float*)p)[i] = f; }
}

// BIASMODE: 0 = per-col bias[], 1 = per-(seg,col) sb[] (NOUT must be 512)
// EPI: 0 = store bf16 to out, 1 = segmax atomicMax(ordered-uint) into outAtomic
template <int BIASMODE, bool RELU, int EPI, int K, int NOUT>
__launch_bounds__(256)
__global__ void k_gemm(const bf16* __restrict__ A, const bf16* __restrict__ Bt,
                       const float* __restrict__ bias, const int* __restrict__ ids,
                       long row_off, bf16* __restrict__ out,
                       unsigned* __restrict__ outAtomic) {
  constexpr int KT = K / 32;
  constexpr int NBX = NOUT / 128;
  __shared__ __align__(16) bf16 sA[2][4096];
  __shared__ __align__(16) bf16 sB[2][4096];
  __shared__ int sIds[128];
  const int tid = threadIdx.x;
  const int wid = tid >> 6, lane = tid & 63;

  // linear id (N fastest) -> bijective XCD swizzle (m204) -> decode N fastest
  const int nwg = NBX * (int)gridDim.y;
  const int orig = (int)blockIdx.y * NBX + (int)blockIdx.x;
  const int q = nwg >> 3, r = nwg & 7;
  const int xcd = orig & 7, lid = orig >> 3;
  const int wg = (xcd < r ? xcd * (q + 1) : r * (q + 1) + (xcd - r) * q) + lid;
  const int n0 = (wg % NBX) * 128;
  const int m0 = (wg / NBX) * 128;

  if ((BIASMODE == 1 || EPI == 1) && tid < 128) sIds[tid] = ids[row_off + m0 + tid];

  // staging: chunk c0 covers LDS (row=c0>>2, slot=c0&3); source chunk pre-swizzled
  // so that LDS(row,slot) = A[row][slot ^ ((row>>1)&3)]  (2-way-max bank aliasing)
  const int c0 = wid * 64 + lane;
  const int srow = c0 >> 2;
  const int schunk = (c0 & 3) ^ ((c0 >> 3) & 3);
  const bf16* gA0 = A + (size_t)(m0 + srow) * K + schunk * 8;
  const bf16* gA1 = gA0 + (size_t)64 * K;
  const bf16* gB0 = Bt + (size_t)(n0 + srow) * K + schunk * 8;
  const bf16* gB1 = gB0 + (size_t)64 * K;
  bf16* sA0 = &sA[0][0];
  bf16* sB0 = &sB[0][0];

  auto STAGE = [&](int b, int kt) {
    const int ko = kt * 32;
    bf16* la = sA0 + b * 4096 + wid * 512;
    bf16* lb = sB0 + b * 4096 + wid * 512;
    gld16(gA0 + ko, la); gld16(gA1 + ko, la + 2048);
    gld16(gB0 + ko, lb); gld16(gB1 + ko, lb + 2048);
  };

  // fragment read offsets (swizzled): row = (wr*64 + i*16 + lr), chunk = lk ^ ((lr>>1)&3)
  const int wr = wid >> 1, wc = wid & 1;
  const int lr = lane & 15, lk = lane >> 4;
  const int swz = (lr >> 1) & 3;
  const int foA = (wr * 64 + lr) * 32 + ((lk ^ swz) * 8);
  const int foB = (wc * 64 + lr) * 32 + ((lk ^ swz) * 8);

  f32x4 acc[4][4];
#pragma unroll
  for (int i = 0; i < 4; ++i)
#pragma unroll
    for (int j = 0; j < 4; ++j) acc[i][j] = {0.f, 0.f, 0.f, 0.f};

  STAGE(0, 0);
  if (KT > 1) STAGE(1, 1);

#pragma unroll 1
  for (int kt = 0; kt < KT - 1; ++kt) {
    asm volatile("s_waitcnt vmcnt(4)" ::: "memory");
    __syncthreads();
    const bf16* pa = sA0 + (kt & 1) * 4096 + foA;
    const bf16* pb = sB0 + (kt & 1) * 4096 + foB;
    bf16x8 af[4], bfr[4];
#pragma unroll
    for (int i = 0; i < 4; ++i) af[i] = *(const bf16x8*)(pa + i * 512);
#pragma unroll
    for (int i = 0; i < 4; ++i) bfr[i] = *(const bf16x8*)(pb + i * 512);
    asm volatile("s_waitcnt lgkmcnt(0)" ::: "memory");
    __syncthreads();
    if (kt + 2 < KT) STAGE(kt & 1, kt + 2);
#pragma unroll
    for (int i = 0; i < 4; ++i)
#pragma unroll
      for (int j = 0; j < 4; ++j)
        acc[i][j] = __builtin_amdgcn_mfma_f32_16x16x32_bf16(af[i], bfr[j], acc[i][j], 0, 0, 0);
  }
  // last K-tile: everything must have landed
  {
    asm volatile("s_waitcnt vmcnt(0)" ::: "memory");
    __syncthreads();
    const bf16* pa = sA0 + ((KT - 1) & 1) * 4096 + foA;
    const bf16* pb = sB0 + ((KT - 1) & 1) * 4096 + foB;
    bf16x8 af[4], bfr[4];
#pragma unroll
    for (int i = 0; i < 4; ++i) af[i] = *(const bf16x8*)(pa + i * 512);
#pragma unroll
    for (int i = 0; i < 4; ++i) bfr[i] = *(const bf16x8*)(pb + i * 512);
#pragma unroll
    for (int i = 0; i < 4; ++i)
#pragma unroll
      for (int j = 0; j < 4; ++j)
        acc[i][j] = __builtin_amdgcn_mfma_f32_16x16x32_bf16(af[i], bfr[j], acc[i][j], 0, 0, 0);
  }

  if constexpr (EPI == 0) {
#pragma unroll
    for (int j = 0; j < 4; ++j) {
      const int col = n0 + wc * 64 + j * 16 + lr;
      float bcol = (BIASMODE == 0) ? bias[col] : 0.f;
#pragma unroll
      for (int i = 0; i < 4; ++i) {
#pragma unroll
        for (int q2 = 0; q2 < 4; ++q2) {
          const int rl = wr * 64 + i * 16 + lk * 4 + q2;
          float v = acc[i][j][q2];
          if constexpr (BIASMODE == 0) v += bcol;
          else v += bias[(size_t)sIds[rl] * 512 + col];
          if constexpr (RELU) v = fmaxf(v, 0.f);
          out[(size_t)(m0 + rl) * NOUT + col] = (bf16)v;
        }
      }
    }
  } else {
    const int sLo = sIds[wr * 64], sHi = sIds[wr * 64 + 63];
#pragma unroll
    for (int j = 0; j < 4; ++j) {
      const int col = n0 + wc * 64 + j * 16 + lr;
      const float bcol = bias[col];
      for (int s = sLo; s <= sHi; ++s) {
        float m = -__builtin_inff();
#pragma unroll
        for (int i = 0; i < 4; ++i)
#pragma unroll
          for (int q2 = 0; q2 < 4; ++q2) {
            const int rl = wr * 64 + i * 16 + lk * 4 + q2;
            float v = acc[i][j][q2] + bcol;
            m = (sIds[rl] == s) ? fmaxf(m, v) : m;
          }
        m = fmaxf(m, __shfl_xor(m, 16));
        m = fmaxf(m, __shfl_xor(m, 32));
        if (lane < 16) atomicMax(&outAtomic[(size_t)s * 512 + col], f2ord(m));
      }
    }
  }
}

static inline long lmin(long a, long b) { return a < b ? a : b; }

extern "C" void kernel_launch(void* const* d_in, const int* in_sizes, int n_in,
                              void* d_out, int out_size, void* d_ws, size_t ws_size,
                              hipStream_t stream) {
  const float* pos = (const float*)d_in[0];
  const int* ids = (const int*)d_in[1];
  const float* W1 = (const float*)d_in[2]; const float* b1 = (const float*)d_in[3];
  const float* W2 = (const float*)d_in[4]; const float* b2 = (const float*)d_in[5];
  const float* W3 = (const float*)d_in[6]; const float* b3 = (const float*)d_in[7];
  const float* W4 = (const float*)d_in[8]; const float* b4 = (const float*)d_in[9];
  const float* W5 = (const float*)d_in[10]; const float* b5 = (const float*)d_in[11];

  char* ws = (char*)d_ws;
  size_t off = 0;
  auto alloc = [&](size_t bytes) -> char* {
    off = (off + 255) & ~(size_t)255;
    char* p = ws + off; off += bytes; return p;
  };
  bf16* Wt1  = (bf16*)alloc(128 * 256 * 2);
  bf16* Wt2  = (bf16*)alloc(256 * 512 * 2);
  bf16* Wt3  = (bf16*)alloc(512 * 512 * 2);
  bf16* Wt4a = (bf16*)alloc(128 * 512 * 2);
  bf16* Wt5  = (bf16*)alloc(512 * 512 * 2);
  unsigned* g_ord = (unsigned*)alloc(64 * 512 * 4);
  float* sb = (float*)alloc(64 * 512 * 4);

  const size_t per_row = (128 + 256 + 512) * 2;
  size_t fixed_end = (off + 255) & ~(size_t)255;
  long avail = (long)ws_size - (long)fixed_end - 8192;
  long chunk = (avail / (long)per_row) & ~127L;
  if (chunk > N_PTS) chunk = N_PTS;
  if (chunk < 128) chunk = 128;

  bf16* Xbf = (bf16*)alloc((size_t)chunk * 128 * 2);
  bf16* h1  = (bf16*)alloc((size_t)chunk * 256 * 2);
  bf16* h2  = (bf16*)alloc((size_t)chunk * 512 * 2);  // also z1 in phase 2

  const int nChunks = (int)((N_PTS + chunk - 1) / chunk);

  k_init<<<dim3(128), dim3(256), 0, stream>>>(g_ord, (unsigned*)d_out);
  k_convWt<<<dim3((128 * 256 + 255) / 256), dim3(256), 0, stream>>>(W1, Wt1, 128, 256);
  k_convWt<<<dim3((256 * 512 + 255) / 256), dim3(256), 0, stream>>>(W2, Wt2, 256, 512);
  k_convWt<<<dim3((512 * 512 + 255) / 256), dim3(256), 0, stream>>>(W3, Wt3, 512, 512);
  k_convWt<<<dim3((128 * 512 + 255) / 256), dim3(256), 0, stream>>>(W4, Wt4a, 128, 512);
  k_convWt<<<dim3((512 * 512 + 255) / 256), dim3(256), 0, stream>>>(W5, Wt5, 512, 512);

  // phase 1: mlp1 + fused segmax -> g_ord
  for (long o = 0; o < N_PTS; o += chunk) {
    long rows = lmin(chunk, N_PTS - o);
    long n4 = rows * 32;
    long cb = lmin(2048, (n4 + 255) / 256);
    k_convX<<<dim3((unsigned)cb), dim3(256), 0, stream>>>(pos + o * 128, Xbf, n4);
    unsigned mb = (unsigned)(rows / 128);
    k_gemm<0, true, 0, 128, 256><<<dim3(2, mb), dim3(256), 0, stream>>>(Xbf, Wt1, b1, ids, o, h1, nullptr);
    k_gemm<0, true, 0, 256, 512><<<dim3(4, mb), dim3(256), 0, stream>>>(h1, Wt2, b2, ids, o, h2, nullptr);
    k_gemm<0, false, 1, 512, 512><<<dim3(4, mb), dim3(256), 0, stream>>>(h2, Wt3, b3, ids, o, nullptr, g_ord);
  }
  k_segbias<<<dim3(64), dim3(512), 0, stream>>>(g_ord, W4, b4, sb);
  // phase 2: z1 = relu(X@W4a + sb[seg]); out = segmax(z1@W5 + b5)
  for (long o = 0; o < N_PTS; o += chunk) {
    long rows = lmin(chunk, N_PTS - o);
    if (nChunks > 1) {
      long n4 = rows * 32;
      long cb = lmin(2048, (n4 + 255) / 256);
      k_convX<<<dim3((unsigned)cb), dim3(256), 0, stream>>>(pos + o * 128, Xbf, n4);
    }
    unsigned mb = (unsigned)(rows / 128);
    k_gemm<1, true, 0, 128, 512><<<dim3(4, mb), dim3(256), 0, stream>>>(Xbf, Wt4a, sb, ids, o, h2, nullptr);
    k_gemm<0, false, 1, 512, 512><<<dim3(4, mb), dim3(256), 0, stream>>>(h2, Wt5, b5, ids, o, nullptr, (unsigned*)d_out);
  }
  k_decode<<<dim3(128), dim3(256), 0, stream>>>((unsigned*)d_out, 64 * 512);
}